// Round 1
// baseline (192.432 us; speedup 1.0000x reference)
//
#include <hip/hip_runtime.h>
#include <hip/hip_bf16.h>

// SelfAttention: B=4, S=4096, Din=768, Dout=64.
// R1 strategy: bf16 MFMA everywhere (fp32 accum), flash-attention style.
//   k0: pack W -> bf16 [192][768]
//   k1: qkv proj GEMM (16x16x32 bf16 MFMA), q/k row-major bf16, v transposed [64][S]
//   k2: flash attn, 1 wave = 16 q-rows, KV tile = 32, P via LDS (C-layout -> A-layout)

typedef __attribute__((ext_vector_type(8))) __bf16 bf16x8;
typedef __attribute__((ext_vector_type(4))) float  f32x4;

constexpr int BATCH = 4;
constexpr int SEQ   = 4096;
constexpr int DIN   = 768;
constexpr int NTOT  = 192;          // 3 * 64 packed output features
constexpr int MROWS = BATCH * SEQ;  // 16384

__device__ __forceinline__ f32x4 mfma16(bf16x8 a, bf16x8 b, f32x4 c) {
    return __builtin_amdgcn_mfma_f32_16x16x32_bf16(a, b, c, 0, 0, 0);
}

// ---------------- k0: pack Wq|Wk|Wv (fp32 [64][768] each) -> bf16 [192][768]
__global__ __launch_bounds__(256) void convert_w(
        const float* __restrict__ Wq, const float* __restrict__ Wk,
        const float* __restrict__ Wv, __bf16* __restrict__ wb) {
    int i = blockIdx.x * 256 + threadIdx.x;
    if (i >= NTOT * DIN) return;
    int n = i / DIN;
    const float* src = (n < 64) ? Wq : (n < 128) ? Wk : Wv;
    wb[i] = (__bf16)src[(n & 63) * DIN + (i % DIN)];
}

// ---------------- k1: q,k,v = x @ W^T   (M=16384, N=192, K=768)
// block = 4 waves; wave w owns rows [blk*64 + w*16, +16), all 12 n-tiles.
__global__ __launch_bounds__(256) void qkv_proj(
        const float* __restrict__ x, const __bf16* __restrict__ wb,
        __bf16* __restrict__ q, __bf16* __restrict__ k, __bf16* __restrict__ vT) {
    const int wave = threadIdx.x >> 6, lane = threadIdx.x & 63;
    const int lr = lane & 15;            // A-row / B-col lane index
    const int lk = (lane >> 4) * 8;      // k offset within 32-wide K step
    const int row = blockIdx.x * 64 + wave * 16 + lr;

    f32x4 acc[12];
#pragma unroll
    for (int t = 0; t < 12; ++t) acc[t] = f32x4{0.f, 0.f, 0.f, 0.f};

    for (int k0 = 0; k0 < DIN; k0 += 32) {
        // A fragment: x[row][k0+lk .. +8], fp32 -> bf16
        const float* xp = x + (size_t)row * DIN + k0 + lk;
        float4 xa = *(const float4*)(xp);
        float4 xb = *(const float4*)(xp + 4);
        bf16x8 af;
        af[0] = (__bf16)xa.x; af[1] = (__bf16)xa.y; af[2] = (__bf16)xa.z; af[3] = (__bf16)xa.w;
        af[4] = (__bf16)xb.x; af[5] = (__bf16)xb.y; af[6] = (__bf16)xb.z; af[7] = (__bf16)xb.w;
#pragma unroll
        for (int t = 0; t < 12; ++t) {
            bf16x8 bf = *(const bf16x8*)(wb + (size_t)(t * 16 + lr) * DIN + k0 + lk);
            acc[t] = mfma16(af, bf, acc[t]);
        }
    }

    // D layout: row=(lane>>4)*4+r, col=lane&15 (within each 16-wide n-tile)
    const int orow = blockIdx.x * 64 + wave * 16 + (lane >> 4) * 4;
#pragma unroll
    for (int t = 0; t < 12; ++t) {
        int n = t * 16 + lr;
#pragma unroll
        for (int r = 0; r < 4; ++r) {
            int m = orow + r;
            __bf16 hv = (__bf16)acc[t][r];
            if (n < 64) {
                q[(size_t)m * 64 + n] = hv;
            } else if (n < 128) {
                k[(size_t)m * 64 + (n - 64)] = hv;
            } else {
                int b = m >> 12, s = m & (SEQ - 1);
                vT[(size_t)b * 64 * SEQ + (size_t)(n - 128) * SEQ + s] = hv;
            }
        }
    }
}

// ---------------- k2: flash attention. grid = (SEQ/64, BATCH), 4 waves/block.
// wave owns 16 q-rows; KV tile = 32 (2 j-subtiles of 16).
__global__ __launch_bounds__(256) void attn(
        const __bf16* __restrict__ q, const __bf16* __restrict__ k,
        const __bf16* __restrict__ vT, float* __restrict__ out) {
    const int wave = threadIdx.x >> 6, lane = threadIdx.x & 63;
    const int b = blockIdx.y;
    const int q0 = blockIdx.x * 64 + wave * 16;
    const int lr = lane & 15;
    const int lk = (lane >> 4) * 8;

    const __bf16* qp = q  + (size_t)b * SEQ * 64;
    const __bf16* kp = k  + (size_t)b * SEQ * 64;
    const __bf16* vp = vT + (size_t)b * 64 * SEQ;

    // Q fragments (loop-invariant): A-layout row=lr, k=lk+e (+32 for kk=1)
    bf16x8 qf0 = *(const bf16x8*)(qp + (size_t)(q0 + lr) * 64 + lk);
    bf16x8 qf1 = *(const bf16x8*)(qp + (size_t)(q0 + lr) * 64 + 32 + lk);

    f32x4 acc_o[4];
#pragma unroll
    for (int t = 0; t < 4; ++t) acc_o[t] = f32x4{0.f, 0.f, 0.f, 0.f};
    float m_run[4], l_run[4];
#pragma unroll
    for (int r = 0; r < 4; ++r) { m_run[r] = -1e30f; l_run[r] = 0.f; }

    // per-wave double-buffered P tile (C-layout -> A-layout round trip)
    __shared__ __align__(16) __bf16 plds[4][2][16][32];

    for (int kv0 = 0; kv0 < SEQ; kv0 += 32) {
        // ---- S = Q K^T * 0.125 (two 16x16 tiles along kv)
        f32x4 s[2];
#pragma unroll
        for (int j = 0; j < 2; ++j) {
            const __bf16* kr = kp + (size_t)(kv0 + j * 16 + lr) * 64 + lk;
            bf16x8 kf0 = *(const bf16x8*)(kr);
            bf16x8 kf1 = *(const bf16x8*)(kr + 32);
            f32x4 a = f32x4{0.f, 0.f, 0.f, 0.f};
            a = mfma16(qf0, kf0, a);
            a = mfma16(qf1, kf1, a);
            s[j] = a;
        }

        // ---- online softmax (rows spread over reg r; cols over lane&15 x j)
        float al[4];
#pragma unroll
        for (int r = 0; r < 4; ++r) {
            float v0 = s[0][r] * 0.125f, v1 = s[1][r] * 0.125f;
            s[0][r] = v0; s[1][r] = v1;
            float mr = fmaxf(v0, v1);
            mr = fmaxf(mr, __shfl_xor(mr, 1));
            mr = fmaxf(mr, __shfl_xor(mr, 2));
            mr = fmaxf(mr, __shfl_xor(mr, 4));
            mr = fmaxf(mr, __shfl_xor(mr, 8));
            float mn = fmaxf(m_run[r], mr);
            al[r] = __expf(m_run[r] - mn);   // first iter: exp(-1e30)=0
            m_run[r] = mn;
        }
#pragma unroll
        for (int r = 0; r < 4; ++r) {
            float p0 = __expf(s[0][r] - m_run[r]);
            float p1 = __expf(s[1][r] - m_run[r]);
            s[0][r] = p0; s[1][r] = p1;
            float su = p0 + p1;
            su += __shfl_xor(su, 1);
            su += __shfl_xor(su, 2);
            su += __shfl_xor(su, 4);
            su += __shfl_xor(su, 8);
            l_run[r] = l_run[r] * al[r] + su;
        }

        // ---- P (C-layout) -> LDS -> A-layout fragment
        __bf16 (*pw)[32] = plds[wave][(kv0 >> 5) & 1];
#pragma unroll
        for (int r = 0; r < 4; ++r) {
            int prow = (lane >> 4) * 4 + r;
            pw[prow][lr]      = (__bf16)s[0][r];
            pw[prow][lr + 16] = (__bf16)s[1][r];
        }
        asm volatile("s_waitcnt lgkmcnt(0)" ::: "memory");
        bf16x8 pf = *(const bf16x8*)(&pw[lr][lk]);

        // ---- O = O*alpha + P V  (V^T rows are d, so B-frag is contiguous)
#pragma unroll
        for (int t = 0; t < 4; ++t) {
            f32x4 a = acc_o[t];
#pragma unroll
            for (int r = 0; r < 4; ++r) a[r] *= al[r];
            bf16x8 vf = *(const bf16x8*)(vp + (size_t)(t * 16 + lr) * SEQ + kv0 + lk);
            acc_o[t] = mfma16(pf, vf, a);
        }
    }

    // ---- epilogue: divide by row sum, store fp32
    float inv[4];
#pragma unroll
    for (int r = 0; r < 4; ++r) inv[r] = 1.f / l_run[r];
    float* ob = out + ((size_t)b * SEQ + q0) * 64;
#pragma unroll
    for (int t = 0; t < 4; ++t)
#pragma unroll
        for (int r = 0; r < 4; ++r)
            ob[(size_t)((lane >> 4) * 4 + r) * 64 + t * 16 + lr] = acc_o[t][r] * inv[r];
}

extern "C" void kernel_launch(void* const* d_in, const int* in_sizes, int n_in,
                              void* d_out, int out_size, void* d_ws, size_t ws_size,
                              hipStream_t stream) {
    const float* x  = (const float*)d_in[0];
    const float* Wq = (const float*)d_in[1];
    const float* Wk = (const float*)d_in[2];
    const float* Wv = (const float*)d_in[3];
    float* out = (float*)d_out;

    char* ws = (char*)d_ws;
    // ws layout: wb 294912 B | q 2 MiB | k 2 MiB | vT 2 MiB  (total ~6.3 MiB)
    __bf16* wb = (__bf16*)(ws);
    __bf16* qb = (__bf16*)(ws + 294912);
    __bf16* kb = (__bf16*)(ws + 294912 + 2097152);
    __bf16* vT = (__bf16*)(ws + 294912 + 2u * 2097152);

    convert_w<<<dim3((NTOT * DIN + 255) / 256), dim3(256), 0, stream>>>(Wq, Wk, Wv, wb);
    qkv_proj<<<dim3(MROWS / 64), dim3(256), 0, stream>>>(x, wb, qb, kb, vT);
    attn<<<dim3(SEQ / 64, BATCH), dim3(256), 0, stream>>>(qb, kb, vT, out);
}